// Round 2
// baseline (335.892 us; speedup 1.0000x reference)
//
#include <hip/hip_runtime.h>
#include <hip/hip_bf16.h>

#define BB 8
#define SS 2048
#define NN 1024
#define MT (BB*SS)   // 16384
#define NKC 8        // key chunks in flash (grid = 8*16*NKC = 1024 -> 4 blocks/CU)

typedef __attribute__((ext_vector_type(8))) short bf16x8;
typedef __attribute__((ext_vector_type(4))) float f32x4;
typedef unsigned short u16;
typedef unsigned int u32;

__device__ __forceinline__ u16 f2bf(float f) {
  u32 u = __float_as_uint(f);
  u += 0x7fff + ((u >> 16) & 1);
  return (u16)(u >> 16);
}
__device__ __forceinline__ float bf2f(u16 h) {
  return __uint_as_float(((u32)h) << 16);
}

typedef __attribute__((address_space(1))) void GV;
typedef __attribute__((address_space(3))) void LV;
__device__ __forceinline__ void cp16(const void* g, void* l) {
  __builtin_amdgcn_global_load_lds((GV*)g, (LV*)l, 16, 0, 0);
}

// ---------------- prep: cast outer -> bf16, rowsum -> r ----------------
__global__ __launch_bounds__(256) void prep_x_kernel(const float* __restrict__ outer,
                                                     u16* __restrict__ Xb,
                                                     float* __restrict__ r) {
  int row = blockIdx.x;
  int tid = threadIdx.x;
  const float4* src = (const float4*)(outer + (size_t)row * NN);
  float4 v = src[tid];
  ushort4 o;
  o.x = f2bf(v.x); o.y = f2bf(v.y); o.z = f2bf(v.z); o.w = f2bf(v.w);
  ((ushort4*)(Xb + (size_t)row * NN))[tid] = o;
  float s = (v.x + v.y) + (v.z + v.w);
  for (int off = 32; off > 0; off >>= 1) s += __shfl_down(s, off);
  __shared__ float red[4];
  int w = tid >> 6, lane = tid & 63;
  if (lane == 0) red[w] = s;
  __syncthreads();
  if (tid == 0) r[row] = (red[0] + red[1]) + (red[2] + red[3]);
}

// ---------------- prep: cast weights -> bf16 (rows 0..1023 = Wq, 1024.. = Wk) --
__global__ __launch_bounds__(256) void prep_w_kernel(const float* __restrict__ Wq,
                                                     const float* __restrict__ Wk,
                                                     const float* __restrict__ bq,
                                                     const float* __restrict__ bk,
                                                     u16* __restrict__ Wb,
                                                     float* __restrict__ bb) {
  int idx = blockIdx.x * 256 + threadIdx.x;   // 0 .. 524287 (x4 elems)
  int e = idx * 4;
  int rowm = e >> 10;
  int col = e & 1023;
  const float* srcp = (rowm < NN) ? (Wq + (size_t)rowm * NN + col)
                                  : (Wk + (size_t)(rowm - NN) * NN + col);
  float4 v = *(const float4*)srcp;
  ushort4 o; o.x = f2bf(v.x); o.y = f2bf(v.y); o.z = f2bf(v.z); o.w = f2bf(v.w);
  *(ushort4*)(Wb + (size_t)e) = o;
  if (idx < 2 * NN) bb[idx] = (idx < NN) ? bq[idx] : bk[idx - NN];
}

// ---------------- stage 1 GEMM: C[row][m] = sigmoid(X.Wb^T + bb) - 0.5 (bf16) --
// grid = (16 tn, 128 tm): tn fast so consecutive blocks share the X-tile (L2 reuse)
__global__ __launch_bounds__(256) void gemm1_kernel(const u16* __restrict__ X,
                                                    const u16* __restrict__ W,
                                                    const float* __restrict__ bb,
                                                    u16* __restrict__ C) {
  __shared__ u16 lA[128 * 32];
  __shared__ u16 lB[128 * 32];
  int tn = blockIdx.x;   // 16  (fast index -> W/N sweep shares X-tile in L2)
  int tm = blockIdx.y;   // 128
  int tid = threadIdx.x;
  int w = tid >> 6, lane = tid & 63;
  int srow = tid >> 2;
  int scol = (tid & 3) * 8;
  const u16* gA = X + (size_t)(tm * 128 + srow) * NN + scol;
  const u16* gB = W + (size_t)(tn * 128 + srow) * NN + scol;
  u16* dA = &lA[srow * 32 + scol];
  u16* dB = &lB[srow * 32 + scol];
  const u16* pa0 = &lA[(w * 32 + (lane & 15)) * 32 + (lane >> 4) * 8];
  const u16* pb0 = &lB[(lane & 15) * 32 + (lane >> 4) * 8];
  f32x4 acc[2][8] = {};
  for (int kk = 0; kk < NN; kk += 32) {
    cp16(gA, dA);
    cp16(gA + 64 * NN, dA + 64 * 32);
    cp16(gB, dB);
    cp16(gB + 64 * NN, dB + 64 * 32);
    gA += 32; gB += 32;
    __syncthreads();
    bf16x8 a0 = *(const bf16x8*)(pa0);
    bf16x8 a1 = *(const bf16x8*)(pa0 + 16 * 32);
#pragma unroll
    for (int j = 0; j < 8; j++) {
      bf16x8 bfrag = *(const bf16x8*)(pb0 + j * 16 * 32);
      acc[0][j] = __builtin_amdgcn_mfma_f32_16x16x32_bf16(a0, bfrag, acc[0][j], 0, 0, 0);
      acc[1][j] = __builtin_amdgcn_mfma_f32_16x16x32_bf16(a1, bfrag, acc[1][j], 0, 0, 0);
    }
    __syncthreads();
  }
  int quad = lane >> 4;
  int colb = tn * 128 + (lane & 15);
#pragma unroll
  for (int i = 0; i < 2; i++) {
#pragma unroll
    for (int j = 0; j < 8; j++) {
      int col = colb + j * 16;
      float bias = bb[col];
#pragma unroll
      for (int rg = 0; rg < 4; rg++) {
        int row = tm * 128 + w * 32 + i * 16 + quad * 4 + rg;
        float v = acc[i][j][rg] + bias;
        float sg = 1.0f / (1.0f + __expf(-v));
        C[(size_t)row * 2048 + col] = f2bf(sg - 0.5f);
      }
    }
  }
}

// ---------------- column bias: kb = 0.5*sum_i k'[row,i] + mask ----------------
__global__ __launch_bounds__(256) void kbias_kernel(const u16* __restrict__ C,
                                                    const float* __restrict__ mask,
                                                    float* __restrict__ kb) {
  int row = blockIdx.x;
  int tid = threadIdx.x;
  ushort4 u = ((const ushort4*)(C + (size_t)row * 2048 + 1024))[tid];
  float s = (bf2f(u.x) + bf2f(u.y)) + (bf2f(u.z) + bf2f(u.w));
  for (int off = 32; off > 0; off >>= 1) s += __shfl_down(s, off);
  __shared__ float red[4];
  int w = tid >> 6, lane = tid & 63;
  if (lane == 0) red[w] = s;
  __syncthreads();
  if (tid == 0) kb[row] = 0.5f * ((red[0] + red[1]) + (red[2] + red[3])) + mask[row];
}

// ---------------- flash: logits = q'.k'^T + kb, online softmax, dot with r ----
__global__ __launch_bounds__(256) void flash_kernel(const u16* __restrict__ C,
                                                    const float* __restrict__ kb,
                                                    const float* __restrict__ r,
                                                    float* __restrict__ pm,
                                                    float* __restrict__ pl,
                                                    float* __restrict__ pt) {
  __shared__ u16 lA[128 * 32];
  __shared__ u16 lB[128 * 32];
  int bid = blockIdx.x;           // 8 * 16 * NKC = 1024
  int kc = bid & (NKC - 1);
  int qt = (bid >> 3) & 15;
  int b  = bid >> 7;
  int tid = threadIdx.x;
  int w = tid >> 6, lane = tid & 63;
  int srow = tid >> 2;
  int scol = (tid & 3) * 8;
  const u16* gAbase = C + (size_t)(b * SS + qt * 128 + srow) * 2048 + scol;
  u16* dA = &lA[srow * 32 + scol];
  u16* dB = &lB[srow * 32 + scol];
  const u16* pa0 = &lA[(w * 32 + (lane & 15)) * 32 + (lane >> 4) * 8];
  const u16* pb0 = &lB[(lane & 15) * 32 + (lane >> 4) * 8];
  int quad = lane >> 4;
  float m_i[2][4], l_i[2][4], t_i[2][4];
#pragma unroll
  for (int i = 0; i < 2; i++)
#pragma unroll
    for (int rg = 0; rg < 4; rg++) { m_i[i][rg] = -1e30f; l_i[i][rg] = 0.f; t_i[i][rg] = 0.f; }

  for (int kt = 0; kt < 2; kt++) {
    int key0 = kc * 256 + kt * 128;
    const u16* gA = gAbase;
    const u16* gB = C + (size_t)(b * SS + key0 + srow) * 2048 + 1024 + scol;
    f32x4 acc[2][8] = {};
    for (int kk = 0; kk < NN; kk += 32) {
      cp16(gA, dA);
      cp16(gA + 64 * 2048, dA + 64 * 32);
      cp16(gB, dB);
      cp16(gB + 64 * 2048, dB + 64 * 32);
      gA += 32; gB += 32;
      __syncthreads();
      bf16x8 a0 = *(const bf16x8*)(pa0);
      bf16x8 a1 = *(const bf16x8*)(pa0 + 16 * 32);
#pragma unroll
      for (int j = 0; j < 8; j++) {
        bf16x8 bfrag = *(const bf16x8*)(pb0 + j * 16 * 32);
        acc[0][j] = __builtin_amdgcn_mfma_f32_16x16x32_bf16(a0, bfrag, acc[0][j], 0, 0, 0);
        acc[1][j] = __builtin_amdgcn_mfma_f32_16x16x32_bf16(a1, bfrag, acc[1][j], 0, 0, 0);
      }
      __syncthreads();
    }
    float kbv[8], rv[8];
    int colg = b * SS + key0 + (lane & 15);
#pragma unroll
    for (int j = 0; j < 8; j++) { kbv[j] = kb[colg + j * 16]; rv[j] = r[colg + j * 16]; }
#pragma unroll
    for (int i = 0; i < 2; i++) {
#pragma unroll
      for (int rg = 0; rg < 4; rg++) {
        float lg[8];
        float tmax = -1e30f;
#pragma unroll
        for (int j = 0; j < 8; j++) { lg[j] = acc[i][j][rg] + kbv[j]; tmax = fmaxf(tmax, lg[j]); }
#pragma unroll
        for (int off = 1; off < 16; off <<= 1) tmax = fmaxf(tmax, __shfl_xor(tmax, off));
        float mnew = fmaxf(m_i[i][rg], tmax);
        float alpha = __expf(m_i[i][rg] - mnew);
        float rs = 0.f, rt = 0.f;
#pragma unroll
        for (int j = 0; j < 8; j++) {
          float p = __expf(lg[j] - mnew);
          rs += p; rt += p * rv[j];
        }
#pragma unroll
        for (int off = 1; off < 16; off <<= 1) { rs += __shfl_xor(rs, off); rt += __shfl_xor(rt, off); }
        l_i[i][rg] = l_i[i][rg] * alpha + rs;
        t_i[i][rg] = t_i[i][rg] * alpha + rt;
        m_i[i][rg] = mnew;
      }
    }
  }
  if ((lane & 15) == 0) {
#pragma unroll
    for (int i = 0; i < 2; i++)
#pragma unroll
      for (int rg = 0; rg < 4; rg++) {
        int grow = b * SS + qt * 128 + w * 32 + i * 16 + quad * 4 + rg;
        pm[grow * NKC + kc] = m_i[i][rg];
        pl[grow * NKC + kc] = l_i[i][rg];
        pt[grow * NKC + kc] = t_i[i][rg];
      }
  }
}

// ---------------- combine key-chunk partials ----------------
__global__ __launch_bounds__(256) void fixup_kernel(const float* __restrict__ pm,
                                                    const float* __restrict__ pl,
                                                    const float* __restrict__ pt,
                                                    float* __restrict__ out) {
  int row = blockIdx.x * 256 + threadIdx.x;
  float Mx = -1e30f;
#pragma unroll
  for (int c = 0; c < NKC; c++) Mx = fmaxf(Mx, pm[row * NKC + c]);
  float L = 0.f, T = 0.f;
#pragma unroll
  for (int c = 0; c < NKC; c++) {
    float a = __expf(pm[row * NKC + c] - Mx);
    L += pl[row * NKC + c] * a;
    T += pt[row * NKC + c] * a;
  }
  out[row] = T / L;
}

extern "C" void kernel_launch(void* const* d_in, const int* in_sizes, int n_in,
                              void* d_out, int out_size, void* d_ws, size_t ws_size,
                              hipStream_t stream) {
  const float* outer = (const float*)d_in[0];
  const float* mask  = (const float*)d_in[1];
  const float* Wk    = (const float*)d_in[2];
  const float* bk    = (const float*)d_in[3];
  const float* Wq    = (const float*)d_in[4];
  const float* bq    = (const float*)d_in[5];
  float* out = (float*)d_out;

  char* ws = (char*)d_ws;
  size_t off = 0;
  auto alloc = [&](size_t bytes) -> void* {
    void* p = ws + off;
    off = (off + bytes + 255) & ~(size_t)255;
    return p;
  };
  u16* Xb  = (u16*)alloc((size_t)MT * NN * 2);       // 32 MB bf16 outer
  u16* Wb  = (u16*)alloc((size_t)2048 * NN * 2);     // 4 MB bf16 [Wq;Wk]
  u16* Cq  = (u16*)alloc((size_t)MT * 2048 * 2);     // 64 MB bf16 [q'|k']
  float* bb = (float*)alloc(2048 * 4);
  float* rr = (float*)alloc((size_t)MT * 4);
  float* kb = (float*)alloc((size_t)MT * 4);
  float* pm = (float*)alloc((size_t)MT * NKC * 4);
  float* pl = (float*)alloc((size_t)MT * NKC * 4);
  float* pt = (float*)alloc((size_t)MT * NKC * 4);

  prep_x_kernel<<<dim3(MT), dim3(256), 0, stream>>>(outer, Xb, rr);
  prep_w_kernel<<<dim3(2048), dim3(256), 0, stream>>>(Wq, Wk, bq, bk, Wb, bb);
  gemm1_kernel<<<dim3(16, 128), dim3(256), 0, stream>>>(Xb, Wb, bb, Cq);
  kbias_kernel<<<dim3(MT), dim3(256), 0, stream>>>(Cq, mask, kb);
  flash_kernel<<<dim3(8 * 16 * NKC), dim3(256), 0, stream>>>(Cq, kb, rr, pm, pl, pt);
  fixup_kernel<<<dim3(MT / 256), dim3(256), 0, stream>>>(pm, pl, pt, out);
}

// Round 3
// 300.901 us; speedup vs baseline: 1.1163x; 1.1163x over previous
//
#include <hip/hip_runtime.h>
#include <hip/hip_bf16.h>

#define BB 8
#define SS 2048
#define NN 1024
#define MT (BB*SS)   // 16384
#define NKC 16       // one 128-key tile per block; grid = 8*16*16 = 2048

typedef __attribute__((ext_vector_type(8))) short bf16x8;
typedef __attribute__((ext_vector_type(4))) float f32x4;
typedef unsigned short u16;
typedef unsigned int u32;

__device__ __forceinline__ u16 f2bf(float f) {
  u32 u = __float_as_uint(f);
  u += 0x7fff + ((u >> 16) & 1);
  return (u16)(u >> 16);
}
__device__ __forceinline__ float bf2f(u16 h) {
  return __uint_as_float(((u32)h) << 16);
}

typedef __attribute__((address_space(1))) void GV;
typedef __attribute__((address_space(3))) void LV;
__device__ __forceinline__ void cp16(const void* g, void* l) {
  __builtin_amdgcn_global_load_lds((GV*)g, (LV*)l, 16, 0, 0);
}

// ---------------- prep: cast outer -> bf16, rowsum -> r ----------------
__global__ __launch_bounds__(256) void prep_x_kernel(const float* __restrict__ outer,
                                                     u16* __restrict__ Xb,
                                                     float* __restrict__ r) {
  int row = blockIdx.x;
  int tid = threadIdx.x;
  const float4* src = (const float4*)(outer + (size_t)row * NN);
  float4 v = src[tid];
  ushort4 o;
  o.x = f2bf(v.x); o.y = f2bf(v.y); o.z = f2bf(v.z); o.w = f2bf(v.w);
  ((ushort4*)(Xb + (size_t)row * NN))[tid] = o;
  float s = (v.x + v.y) + (v.z + v.w);
  for (int off = 32; off > 0; off >>= 1) s += __shfl_down(s, off);
  __shared__ float red[4];
  int w = tid >> 6, lane = tid & 63;
  if (lane == 0) red[w] = s;
  __syncthreads();
  if (tid == 0) r[row] = (red[0] + red[1]) + (red[2] + red[3]);
}

// ---------------- prep: cast weights -> bf16 (rows 0..1023 = Wq, 1024.. = Wk) --
__global__ __launch_bounds__(256) void prep_w_kernel(const float* __restrict__ Wq,
                                                     const float* __restrict__ Wk,
                                                     const float* __restrict__ bq,
                                                     const float* __restrict__ bk,
                                                     u16* __restrict__ Wb,
                                                     float* __restrict__ bb) {
  int idx = blockIdx.x * 256 + threadIdx.x;   // 0 .. 524287 (x4 elems)
  int e = idx * 4;
  int rowm = e >> 10;
  int col = e & 1023;
  const float* srcp = (rowm < NN) ? (Wq + (size_t)rowm * NN + col)
                                  : (Wk + (size_t)(rowm - NN) * NN + col);
  float4 v = *(const float4*)srcp;
  ushort4 o; o.x = f2bf(v.x); o.y = f2bf(v.y); o.z = f2bf(v.z); o.w = f2bf(v.w);
  *(ushort4*)(Wb + (size_t)e) = o;
  if (idx < 2 * NN) bb[idx] = (idx < NN) ? bq[idx] : bk[idx - NN];
}

// ---------------- stage 1 GEMM: C[row][m] = sigmoid(X.Wb^T + bb) - 0.5 (bf16) --
// grid = (16 tn, 128 tm): tn fast so consecutive blocks share the X-tile (L2 reuse)
// __launch_bounds__(256,3): force <=~170 regs/wave -> 3 blocks/CU
__global__ __launch_bounds__(256, 3) void gemm1_kernel(const u16* __restrict__ X,
                                                       const u16* __restrict__ W,
                                                       const float* __restrict__ bb,
                                                       u16* __restrict__ C) {
  __shared__ u16 lA[128 * 32];
  __shared__ u16 lB[128 * 32];
  int tn = blockIdx.x;   // 16
  int tm = blockIdx.y;   // 128
  int tid = threadIdx.x;
  int w = tid >> 6, lane = tid & 63;
  int srow = tid >> 2;
  int scol = (tid & 3) * 8;
  const u16* gA = X + (size_t)(tm * 128 + srow) * NN + scol;
  const u16* gB = W + (size_t)(tn * 128 + srow) * NN + scol;
  u16* dA = &lA[srow * 32 + scol];
  u16* dB = &lB[srow * 32 + scol];
  const u16* pa0 = &lA[(w * 32 + (lane & 15)) * 32 + (lane >> 4) * 8];
  const u16* pb0 = &lB[(lane & 15) * 32 + (lane >> 4) * 8];
  f32x4 acc[2][8] = {};
  for (int kk = 0; kk < NN; kk += 32) {
    cp16(gA, dA);
    cp16(gA + 64 * NN, dA + 64 * 32);
    cp16(gB, dB);
    cp16(gB + 64 * NN, dB + 64 * 32);
    gA += 32; gB += 32;
    __syncthreads();
    bf16x8 a0 = *(const bf16x8*)(pa0);
    bf16x8 a1 = *(const bf16x8*)(pa0 + 16 * 32);
#pragma unroll
    for (int j = 0; j < 8; j++) {
      bf16x8 bfrag = *(const bf16x8*)(pb0 + j * 16 * 32);
      acc[0][j] = __builtin_amdgcn_mfma_f32_16x16x32_bf16(a0, bfrag, acc[0][j], 0, 0, 0);
      acc[1][j] = __builtin_amdgcn_mfma_f32_16x16x32_bf16(a1, bfrag, acc[1][j], 0, 0, 0);
    }
    __syncthreads();
  }
  int quad = lane >> 4;
  int colb = tn * 128 + (lane & 15);
#pragma unroll
  for (int i = 0; i < 2; i++) {
#pragma unroll
    for (int j = 0; j < 8; j++) {
      int col = colb + j * 16;
      float bias = bb[col];
#pragma unroll
      for (int rg = 0; rg < 4; rg++) {
        int row = tm * 128 + w * 32 + i * 16 + quad * 4 + rg;
        float v = acc[i][j][rg] + bias;
        float sg = 1.0f / (1.0f + __expf(-v));
        C[(size_t)row * 2048 + col] = f2bf(sg - 0.5f);
      }
    }
  }
}

// ---------------- column bias: kb = 0.5*sum_i k'[row,i] + mask ----------------
__global__ __launch_bounds__(256) void kbias_kernel(const u16* __restrict__ C,
                                                    const float* __restrict__ mask,
                                                    float* __restrict__ kb) {
  int row = blockIdx.x;
  int tid = threadIdx.x;
  ushort4 u = ((const ushort4*)(C + (size_t)row * 2048 + 1024))[tid];
  float s = (bf2f(u.x) + bf2f(u.y)) + (bf2f(u.z) + bf2f(u.w));
  for (int off = 32; off > 0; off >>= 1) s += __shfl_down(s, off);
  __shared__ float red[4];
  int w = tid >> 6, lane = tid & 63;
  if (lane == 0) red[w] = s;
  __syncthreads();
  if (tid == 0) kb[row] = 0.5f * ((red[0] + red[1]) + (red[2] + red[3])) + mask[row];
}

// ---------------- flash: one 128q x 128k tile per block; single-tile softmax --
__global__ __launch_bounds__(256, 3) void flash_kernel(const u16* __restrict__ C,
                                                       const float* __restrict__ kb,
                                                       const float* __restrict__ r,
                                                       float* __restrict__ pm,
                                                       float* __restrict__ pl,
                                                       float* __restrict__ pt) {
  __shared__ u16 lA[128 * 32];
  __shared__ u16 lB[128 * 32];
  int bid = blockIdx.x;           // 8 * 16 * 16 = 2048
  int kc = bid & 15;
  int qt = (bid >> 4) & 15;
  int b  = bid >> 8;
  int tid = threadIdx.x;
  int w = tid >> 6, lane = tid & 63;
  int srow = tid >> 2;
  int scol = (tid & 3) * 8;
  int key0 = kc * 128;
  const u16* gA = C + (size_t)(b * SS + qt * 128 + srow) * 2048 + scol;
  const u16* gB = C + (size_t)(b * SS + key0 + srow) * 2048 + 1024 + scol;
  u16* dA = &lA[srow * 32 + scol];
  u16* dB = &lB[srow * 32 + scol];
  const u16* pa0 = &lA[(w * 32 + (lane & 15)) * 32 + (lane >> 4) * 8];
  const u16* pb0 = &lB[(lane & 15) * 32 + (lane >> 4) * 8];
  int quad = lane >> 4;

  f32x4 acc[2][8] = {};
  for (int kk = 0; kk < NN; kk += 32) {
    cp16(gA, dA);
    cp16(gA + 64 * 2048, dA + 64 * 32);
    cp16(gB, dB);
    cp16(gB + 64 * 2048, dB + 64 * 32);
    gA += 32; gB += 32;
    __syncthreads();
    bf16x8 a0 = *(const bf16x8*)(pa0);
    bf16x8 a1 = *(const bf16x8*)(pa0 + 16 * 32);
#pragma unroll
    for (int j = 0; j < 8; j++) {
      bf16x8 bfrag = *(const bf16x8*)(pb0 + j * 16 * 32);
      acc[0][j] = __builtin_amdgcn_mfma_f32_16x16x32_bf16(a0, bfrag, acc[0][j], 0, 0, 0);
      acc[1][j] = __builtin_amdgcn_mfma_f32_16x16x32_bf16(a1, bfrag, acc[1][j], 0, 0, 0);
    }
    __syncthreads();
  }

  // epilogue: per-row (within this 128-key tile) softmax partials
  float kbv[8], rv[8];
  int colg = b * SS + key0 + (lane & 15);
#pragma unroll
  for (int j = 0; j < 8; j++) { kbv[j] = kb[colg + j * 16]; rv[j] = r[colg + j * 16]; }
#pragma unroll
  for (int i = 0; i < 2; i++) {
#pragma unroll
    for (int rg = 0; rg < 4; rg++) {
      float lg[8];
      float tmax = -1e30f;
#pragma unroll
      for (int j = 0; j < 8; j++) { lg[j] = acc[i][j][rg] + kbv[j]; tmax = fmaxf(tmax, lg[j]); }
#pragma unroll
      for (int off = 1; off < 16; off <<= 1) tmax = fmaxf(tmax, __shfl_xor(tmax, off));
      float rs = 0.f, rt = 0.f;
#pragma unroll
      for (int j = 0; j < 8; j++) {
        float p = __expf(lg[j] - tmax);
        rs += p; rt += p * rv[j];
      }
#pragma unroll
      for (int off = 1; off < 16; off <<= 1) { rs += __shfl_xor(rs, off); rt += __shfl_xor(rt, off); }
      if ((lane & 15) == 0) {
        int grow = b * SS + qt * 128 + w * 32 + i * 16 + quad * 4 + rg;
        pm[grow * NKC + kc] = tmax;
        pl[grow * NKC + kc] = rs;
        pt[grow * NKC + kc] = rt;
      }
    }
  }
}

// ---------------- combine key-chunk partials ----------------
__global__ __launch_bounds__(256) void fixup_kernel(const float* __restrict__ pm,
                                                    const float* __restrict__ pl,
                                                    const float* __restrict__ pt,
                                                    float* __restrict__ out) {
  int row = blockIdx.x * 256 + threadIdx.x;
  float Mx = -1e30f;
#pragma unroll
  for (int c = 0; c < NKC; c++) Mx = fmaxf(Mx, pm[row * NKC + c]);
  float L = 0.f, T = 0.f;
#pragma unroll
  for (int c = 0; c < NKC; c++) {
    float a = __expf(pm[row * NKC + c] - Mx);
    L += pl[row * NKC + c] * a;
    T += pt[row * NKC + c] * a;
  }
  out[row] = T / L;
}

extern "C" void kernel_launch(void* const* d_in, const int* in_sizes, int n_in,
                              void* d_out, int out_size, void* d_ws, size_t ws_size,
                              hipStream_t stream) {
  const float* outer = (const float*)d_in[0];
  const float* mask  = (const float*)d_in[1];
  const float* Wk    = (const float*)d_in[2];
  const float* bk    = (const float*)d_in[3];
  const float* Wq    = (const float*)d_in[4];
  const float* bq    = (const float*)d_in[5];
  float* out = (float*)d_out;

  char* ws = (char*)d_ws;
  size_t off = 0;
  auto alloc = [&](size_t bytes) -> void* {
    void* p = ws + off;
    off = (off + bytes + 255) & ~(size_t)255;
    return p;
  };
  u16* Xb  = (u16*)alloc((size_t)MT * NN * 2);       // 32 MB bf16 outer
  u16* Wb  = (u16*)alloc((size_t)2048 * NN * 2);     // 4 MB bf16 [Wq;Wk]
  u16* Cq  = (u16*)alloc((size_t)MT * 2048 * 2);     // 64 MB bf16 [q'|k']
  float* bb = (float*)alloc(2048 * 4);
  float* rr = (float*)alloc((size_t)MT * 4);
  float* kb = (float*)alloc((size_t)MT * 4);
  float* pm = (float*)alloc((size_t)MT * NKC * 4);
  float* pl = (float*)alloc((size_t)MT * NKC * 4);
  float* pt = (float*)alloc((size_t)MT * NKC * 4);

  prep_x_kernel<<<dim3(MT), dim3(256), 0, stream>>>(outer, Xb, rr);
  prep_w_kernel<<<dim3(2048), dim3(256), 0, stream>>>(Wq, Wk, bq, bk, Wb, bb);
  gemm1_kernel<<<dim3(16, 128), dim3(256), 0, stream>>>(Xb, Wb, bb, Cq);
  kbias_kernel<<<dim3(MT), dim3(256), 0, stream>>>(Cq, mask, kb);
  flash_kernel<<<dim3(8 * 16 * NKC), dim3(256), 0, stream>>>(Cq, kb, rr, pm, pl, pt);
  fixup_kernel<<<dim3(MT / 256), dim3(256), 0, stream>>>(pm, pl, pt, out);
}